// Round 22
// baseline (127.437 us; speedup 1.0000x reference)
//
#include <hip/hip_runtime.h>

// LQR KKT via temporally-parallel Riccati scan — fused persistent kernel.
// Round-22 = r21 + LOCAL LEVEL 0: block t computes BOTH elements t and t+1
// at init (quad GJ16 on 4 waves; 384 GEMM tiles grid-strided), so level 0's
// combine is hop-free and fetch-free. Version-0 publish is dead except t=63
// (only remote v=0 reader is frozen rm=63). rd[0] never set; l=1 WAR deleted
// (first Sb1 write); l>=2 WARs unchanged. Bitwise-identical arithmetic to r21.
// Dims: n_state=32, n_input=16, n_all=48, T=64. Anchors: r19 126.6, r21 126.5.

namespace {

constexpr int NS  = 32;
constexpr int NI  = 16;
constexpr int NA  = 48;
constexpr int TT  = 64;
constexpr int NTH = 256;
constexpr int NBLK = 64;

using ull = unsigned long long;

__device__ __forceinline__ void fma4(float4& a, float s, const float4& b) {
  a.x += s * b.x; a.y += s * b.y; a.z += s * b.z; a.w += s * b.w;
}
__device__ __forceinline__ void fms4(float4& a, float s, const float4& b) {
  a.x -= s * b.x; a.y -= s * b.y; a.z -= s * b.z; a.w -= s * b.w;
}
__device__ __forceinline__ float dot4(const float4& a, const float4& b) {
  return a.x * b.x + a.y * b.y + a.z * b.z + a.w * b.w;
}
__device__ __forceinline__ float rdlane(float v, int l) {
  return __int_as_float(__builtin_amdgcn_readlane(__float_as_int(v), l));
}

// agent-scope relaxed atomic movement (r13..r21-proven primitive)
__device__ __forceinline__ ull ald(const ull* p) {
  return __hip_atomic_load(p, __ATOMIC_RELAXED, __HIP_MEMORY_SCOPE_AGENT);
}
__device__ __forceinline__ void ast(ull* p, ull v) {
  __hip_atomic_store(p, v, __ATOMIC_RELAXED, __HIP_MEMORY_SCOPE_AGENT);
}
__device__ __forceinline__ ull pack2(float x, float y) {
  return (ull)__float_as_uint(x) | ((ull)__float_as_uint(y) << 32);
}
__device__ __forceinline__ float2 unpack2(ull v) {
  return make_float2(__uint_as_float((unsigned)v),
                     __uint_as_float((unsigned)(v >> 32)));
}
__device__ __forceinline__ float4 ald4(const ull* p) {
  ull lo = ald(p), hi = ald(p + 1);
  float2 a = unpack2(lo), b = unpack2(hi);
  return make_float4(a.x, a.y, b.x, b.y);
}
__device__ __forceinline__ void ast4(ull* p, const float4& v) {
  ast(p, pack2(v.x, v.y)); ast(p + 1, pack2(v.z, v.w));
}

// ---- point-to-point flags ----
__device__ __forceinline__ unsigned fld(const unsigned* f) {
  return __hip_atomic_load(f, __ATOMIC_RELAXED, __HIP_MEMORY_SCOPE_AGENT);
}
__device__ __forceinline__ void fst(unsigned* f) {
  __hip_atomic_store(f, 1u, __ATOMIC_RELAXED, __HIP_MEMORY_SCOPE_AGENT);
}
__device__ __forceinline__ void waitf(const unsigned* f) {
  if (threadIdx.x == 0)
    while (fld(f) == 0) __builtin_amdgcn_s_sleep(1);
  __syncthreads();
}
__device__ __forceinline__ void setf(unsigned* f) {
  asm volatile("s_waitcnt vmcnt(0)" ::: "memory");
  __syncthreads();
  if (threadIdx.x == 0) fst(f);
}

template<int K>
__device__ __forceinline__ void tile_outer(const float* Acol0, int lda,
                                           const float* Bcol0, int ldb,
                                           float4 acc[4]) {
  #pragma unroll
  for (int m = 0; m < K; ++m) {
    const float4 va = *(const float4*)(Acol0 + m * lda);
    const float4 vb = *(const float4*)(Bcol0 + m * ldb);
    fma4(acc[0], va.x, vb); fma4(acc[1], va.y, vb);
    fma4(acc[2], va.z, vb); fma4(acc[3], va.w, vb);
  }
}

template<int KQ>
__device__ __forceinline__ void tile_dot(const float* Arow0, int lda,
                                         const float* Brow0, int ldb,
                                         float acc[4][4]) {
  #pragma unroll
  for (int q = 0; q < KQ; ++q) {
    float4 va[4], vb[4];
    #pragma unroll
    for (int r = 0; r < 4; ++r) va[r] = *(const float4*)(Arow0 + r * lda + 4 * q);
    #pragma unroll
    for (int c = 0; c < 4; ++c) vb[c] = *(const float4*)(Brow0 + c * ldb + 4 * q);
    #pragma unroll
    for (int r = 0; r < 4; ++r)
      #pragma unroll
      for (int c = 0; c < 4; ++c) acc[r][c] += dot4(va[r], vb[c]);
  }
}

__device__ __forceinline__ float step_dot(const float4 m[8], float x) {
  float a0 = 0.f, a1 = 0.f, a2 = 0.f, a3 = 0.f;
  #pragma unroll
  for (int q = 0; q < 8; ++q) {
    a0 += rdlane(x, 4 * q + 0) * m[q].x;
    a1 += rdlane(x, 4 * q + 1) * m[q].y;
    a2 += rdlane(x, 4 * q + 2) * m[q].z;
    a3 += rdlane(x, 4 * q + 3) * m[q].w;
  }
  return (a0 + a1) + (a2 + a3);
}

// #binary levels element rm participates in (its final version index)
__device__ __forceinline__ int nlev(int rm) {
  return (rm == TT - 1) ? 0 : (32 - __clz(TT - 1 - rm));
}

__global__ __launch_bounds__(NTH, 1) void lqr_all(
    const float* __restrict__ A, const float* __restrict__ Bm,
    const float* __restrict__ C, const float* __restrict__ x0,
    float* __restrict__ out,
    float* __restrict__ Sb0, float* __restrict__ Sb1,
    float* __restrict__ Mall, unsigned* __restrict__ flg) {
  __shared__ float sC [NA][NA];
  __shared__ float sScr[NA * NA];   // init: C_{t+1} | kmat: G(32x48)+Fu(16x48)
  __shared__ float sAB[NS][NA];
  __shared__ float sRiST[NS][NI];   // S R^{-1}   (element t)
  __shared__ float sBRi [NS][NI];   // B R^{-1}   (element t)
  __shared__ float sAi[NS][NS], sCi[NS][NS], sJi[NS][NS];   // element t
  __shared__ float sAj[NS][NS], sCj[NS][NS], sJj[NS][NS];   // remote / element t+1
  __shared__ float sAjT[NS][36];    // padded transpose (r19)
  __shared__ float sV[NS][NS], sU[NS][NS];
  __shared__ float sY1[NS][NS], sY2[NS][NS], sW[NS][NS];
  __shared__ float sX[NS][NS], sZm[NS][NS];
  __shared__ float sK[NI][NS], sK2[NI][NS];
  __shared__ float sXt0[NS], sXt1[NS];

  // XCD-locality swizzle (r19-proven)
  const int t = ((blockIdx.x & 7) << 3) | (blockIdx.x >> 3);
  const int tid = threadIdx.x, lane = tid & 63, wid = tid >> 6;
  unsigned* wr = flg;              // 7*64
  unsigned* rd = flg + 448;        // 6*64
  unsigned* mf = flg + 832;        // 64

  float (*sC2)[NA]    = (float(*)[NA])sScr;   // C_{t+1} during init
  float (*sRiST2)[NI] = (float(*)[NI])sV;     // element-t+1 GJ outputs
  float (*sBRi2)[NI]  = (float(*)[NI])sU;

  // ========== Phase 0: DUAL element init (t -> sAi/Ci/Ji, t+1 -> sAj/Cj/Jj) =
  {
    const float* Ct = C + (size_t)t * NA * NA;
    for (int e = tid; e < NA * NA; e += NTH) sC[e / NA][e % NA] = Ct[e];
    if (t + 1 < TT) {
      const float* Ct1 = C + (size_t)(t + 1) * NA * NA;
      for (int e = tid; e < NA * NA; e += NTH) sC2[e / NA][e % NA] = Ct1[e];
    }
    for (int e = tid; e < NS * NA; e += NTH) {
      int i = e / NA, j = e % NA;
      sAB[i][j] = (j < NS) ? A[i * NS + j] : Bm[i * NI + (j - NS)];
    }
    __syncthreads();
    // quad GJ16: w0 [Rt|St^T], w1 [Rt|B^T], w2 [Rt1|St1^T], w3 [Rt1|B^T]
    {
      const int ew = wid >> 1, sub = wid & 1;
      if ((ew == 0 || t + 1 < TT) && lane < 48) {
        float (*Cm)[NA] = ew ? sC2 : sC;
        const int c = lane;
        float f[NI];
        if (c < NI) {
          #pragma unroll
          for (int i = 0; i < NI; ++i) f[i] = Cm[NS + i][NS + c];
        } else {
          const int a = c - NI;
          if (sub == 0) {
            #pragma unroll
            for (int i = 0; i < NI; ++i) f[i] = Cm[a][NS + i];
          } else {
            #pragma unroll
            for (int i = 0; i < NI; ++i) f[i] = sAB[a][NS + i];
          }
        }
        #pragma unroll
        for (int k = 0; k < NI; ++k) {
          float mi[NI];
          #pragma unroll
          for (int i = 0; i < NI; ++i) mi[i] = rdlane(f[i], k);
          const float inv = 1.0f / mi[k];
          f[k] *= inv;
          #pragma unroll
          for (int i = 0; i < NI; ++i) if (i != k) f[i] -= mi[i] * f[k];
        }
        if (c >= NI) {
          const int a = c - NI;
          float* D = (sub == 0) ? (ew ? &sRiST2[a][0] : &sRiST[a][0])
                                : (ew ? &sBRi2[a][0]  : &sBRi[a][0]);
          #pragma unroll
          for (int i = 0; i < NI; ++i) D[i] = f[i];
        }
      }
    }
    __syncthreads();
    ull* outA = (ull*)(Sb0 + (size_t)t * 3072);
    ull* outC = outA + 512;
    ull* outJ = outA + 1024;
    const int nwork = (t + 1 < TT) ? 384 : 192;
    for (int u = tid; u < nwork; u += NTH) {
      const int grp = u >> 6, q = u & 63, a = q >> 3, b = q & 7;
      const int ew = (grp >= 3) ? 1 : 0, g3 = grp - 3 * ew;
      float (*Cm)[NA]    = ew ? sC2 : sC;
      float (*RiSTm)[NI] = ew ? sRiST2 : sRiST;
      float (*BRim)[NI]  = ew ? sBRi2 : sBRi;
      float acc[4][4];
      #pragma unroll
      for (int r = 0; r < 4; ++r)
        #pragma unroll
        for (int c = 0; c < 4; ++c) acc[r][c] = 0.f;
      if (g3 == 0) {                  // J = Q - (S R^-1) S^T
        tile_dot<4>(&RiSTm[4 * a][0], NI, &Cm[4 * b][NS], NA, acc);
        float (*dJ)[NS] = ew ? sJj : sJi;
        #pragma unroll
        for (int r = 0; r < 4; ++r) {
          const float4 q4 = *(const float4*)&Cm[4 * a + r][4 * b];
          const float4 v = make_float4(q4.x - acc[r][0], q4.y - acc[r][1],
                                       q4.z - acc[r][2], q4.w - acc[r][3]);
          *(float4*)&dJ[4 * a + r][4 * b] = v;
          if (ew == 0 && t == TT - 1) ast4(outJ + ((4 * a + r) * NS + 4 * b) / 2, v);
        }
      } else if (g3 == 1) {           // A = A - (B R^-1) S^T
        tile_dot<4>(&BRim[4 * a][0], NI, &Cm[4 * b][NS], NA, acc);
        float (*dA)[NS] = ew ? sAj : sAi;
        #pragma unroll
        for (int r = 0; r < 4; ++r) {
          const float4 a4 = *(const float4*)&sAB[4 * a + r][4 * b];
          const float4 v = make_float4(a4.x - acc[r][0], a4.y - acc[r][1],
                                       a4.z - acc[r][2], a4.w - acc[r][3]);
          *(float4*)&dA[4 * a + r][4 * b] = v;
          if (ew == 0 && t == TT - 1) ast4(outA + ((4 * a + r) * NS + 4 * b) / 2, v);
        }
      } else {                        // C = (B R^-1) B^T
        tile_dot<4>(&BRim[4 * a][0], NI, &sAB[4 * b][NS], NA, acc);
        float (*dC)[NS] = ew ? sCj : sCi;
        #pragma unroll
        for (int r = 0; r < 4; ++r) {
          const float4 v = make_float4(acc[r][0], acc[r][1], acc[r][2], acc[r][3]);
          *(float4*)&dC[4 * a + r][4 * b] = v;
          if (ew == 0 && t == TT - 1) ast4(outC + ((4 * a + r) * NS + 4 * b) / 2, v);
        }
      }
    }
  }
  if (t == TT - 1) setf(&wr[0 * 64 + t]);   // only rm=63 has remote v=0 readers
  else __syncthreads();

  // fast combine (r18/r19): own ⊗ remote(sAj,sCj,sJj) via dual-RHS GJ32
  auto combine = [&]() {
    #pragma unroll
    for (int r = 0; r < 4; ++r) {
      const int e = tid + 256 * r, i = e >> 5, j = e & 31;
      sAjT[j][i] = sAj[i][j];
    }
    if (tid < 64) {                 // Ph1: X = I + Ci·Jj
      const int a = tid >> 3, b = tid & 7;
      float4 acc[4] = {make_float4(0,0,0,0), make_float4(0,0,0,0),
                       make_float4(0,0,0,0), make_float4(0,0,0,0)};
      tile_outer<NS>(&sCi[0][4 * a], NS, &sJj[0][4 * b], NS, acc);
      if (a == b) { acc[0].x += 1.f; acc[1].y += 1.f; acc[2].z += 1.f; acc[3].w += 1.f; }
      #pragma unroll
      for (int r = 0; r < 4; ++r) *(float4*)&sX[4 * a + r][4 * b] = acc[r];
    }
    __syncthreads();
    // Ph2: dual GJ32 — wave0 [X|Ai]->V, wave1 [X|Ci]->U
    if (wid < 2) {
      const int c = lane;
      float f[NS];
      if (c < NS) {
        #pragma unroll
        for (int i = 0; i < NS; ++i) f[i] = sX[i][c];
      } else if (wid == 0) {
        #pragma unroll
        for (int i = 0; i < NS; ++i) f[i] = sAi[i][c - NS];
      } else {
        #pragma unroll
        for (int i = 0; i < NS; ++i) f[i] = sCi[i][c - NS];
      }
      #pragma unroll
      for (int k = 0; k < NS; ++k) {
        float mi[NS];
        #pragma unroll
        for (int i = 0; i < NS; ++i) mi[i] = rdlane(f[i], k);
        const float inv = 1.0f / mi[k];
        f[k] *= inv;
        #pragma unroll
        for (int i = 0; i < NS; ++i) if (i != k) f[i] -= mi[i] * f[k];
      }
      if (c >= NS) {
        const int col = c - NS;
        if (wid == 0) {
          #pragma unroll
          for (int i = 0; i < NS; ++i) sV[i][col] = f[i];
        } else {
          #pragma unroll
          for (int i = 0; i < NS; ++i) sU[i][col] = f[i];
        }
      }
    }
    __syncthreads();
    // Ph3: P1 = Jj·V -> sW | A' = Aj·V -> sX | W2 = Aj·U -> sZm
    if (tid < 192) {
      const int grp = tid >> 6, q = tid & 63, a = q >> 3, b = q & 7;
      float4 acc[4] = {make_float4(0,0,0,0), make_float4(0,0,0,0),
                       make_float4(0,0,0,0), make_float4(0,0,0,0)};
      if (grp == 0) {
        tile_outer<NS>(&sJj[0][4 * a], NS, &sV[0][4 * b], NS, acc);
        #pragma unroll
        for (int r = 0; r < 4; ++r) *(float4*)&sW[4 * a + r][4 * b] = acc[r];
      } else if (grp == 1) {
        tile_outer<NS>(&sAjT[0][4 * a], 36, &sV[0][4 * b], NS, acc);
        #pragma unroll
        for (int r = 0; r < 4; ++r) *(float4*)&sX[4 * a + r][4 * b] = acc[r];
      } else {
        tile_outer<NS>(&sAjT[0][4 * a], 36, &sU[0][4 * b], NS, acc);
        #pragma unroll
        for (int r = 0; r < 4; ++r) *(float4*)&sZm[4 * a + r][4 * b] = acc[r];
      }
    }
    __syncthreads();
    // Ph4: J' = Ai^T·P1 + Ji -> sY1 | C' = W2·Aj^T + Cj -> sY2
    if (tid < 64) {
      const int a = tid >> 3, b = tid & 7;
      float4 acc[4] = {make_float4(0,0,0,0), make_float4(0,0,0,0),
                       make_float4(0,0,0,0), make_float4(0,0,0,0)};
      tile_outer<NS>(&sAi[0][4 * a], NS, &sW[0][4 * b], NS, acc);
      #pragma unroll
      for (int r = 0; r < 4; ++r) {
        const float4 j4 = *(const float4*)&sJi[4 * a + r][4 * b];
        acc[r].x += j4.x; acc[r].y += j4.y; acc[r].z += j4.z; acc[r].w += j4.w;
        *(float4*)&sY1[4 * a + r][4 * b] = acc[r];
      }
    } else if (tid < 128) {
      const int q = tid - 64, a = q >> 3, b = q & 7;
      float acc[4][4];
      #pragma unroll
      for (int r = 0; r < 4; ++r)
        #pragma unroll
        for (int c = 0; c < 4; ++c) acc[r][c] = 0.f;
      tile_dot<8>(&sZm[4 * a][0], NS, &sAj[4 * b][0], NS, acc);
      #pragma unroll
      for (int r = 0; r < 4; ++r) {
        const float4 c4 = *(const float4*)&sCj[4 * a + r][4 * b];
        *(float4*)&sY2[4 * a + r][4 * b] =
            make_float4(acc[r][0] + c4.x, acc[r][1] + c4.y,
                        acc[r][2] + c4.z, acc[r][3] + c4.w);
      }
    }
    __syncthreads();
    ((ull*)sAi)[tid] = ((const ull*)sX)[tid];
    ((ull*)sAi)[tid + 256] = ((const ull*)sX)[tid + 256];
    ((ull*)sCi)[tid] = ((const ull*)sY2)[tid];
    ((ull*)sCi)[tid + 256] = ((const ull*)sY2)[tid + 256];
    ((ull*)sJi)[tid] = ((const ull*)sY1)[tid];
    ((ull*)sJi)[tid + 256] = ((const ull*)sY1)[tid + 256];
    __syncthreads();
  };

  // ============ Phase 1: radix-2 scan; level 0 is LOCAL ============
  for (int l = 0; l < 6; ++l) {
    const int off = 1 << l;
    const int rm = t + off;
    if (rm < TT) {
      if (l >= 1) {                         // levels >=1: remote fetch
        const int nlv = nlev(rm);
        const int v = (l < nlv) ? l : nlv;  // frozen-final fallback
        const float* Sin = (v & 1) ? Sb1 : Sb0;
        waitf(&wr[v * 64 + rm]);
        const ull* Ej = (const ull*)(Sin + (size_t)rm * 3072);
        {
          ull r0 = ald(Ej + tid),        r1 = ald(Ej + 256 + tid);
          ull r2 = ald(Ej + 512 + tid),  r3 = ald(Ej + 768 + tid);
          ull r4 = ald(Ej + 1024 + tid), r5 = ald(Ej + 1280 + tid);
          ((ull*)sAj)[tid] = r0; ((ull*)sAj)[tid + 256] = r1;
          ((ull*)sCj)[tid] = r2; ((ull*)sCj)[tid + 256] = r3;
          ((ull*)sJj)[tid] = r4; ((ull*)sJj)[tid + 256] = r5;
        }
        __syncthreads();
        if (v == l && tid == 0) fst(&rd[l * 64 + rm]);
      }
      // level 0: element t+1 already in sAj/sCj/sJj from init
      combine();
      if (l < 5) {                          // level-5 publish dead (r21)
        // WAR: version 0 has no remote readers now -> start at l>=2
        if (l >= 2 && t >= (off >> 1)) waitf(&rd[(l - 1) * 64 + t]);
        ull* Eo = (ull*)((((l + 1) & 1) ? Sb1 : Sb0) + (size_t)t * 3072);
        ast(Eo + tid,        ((const ull*)sAi)[tid]);
        ast(Eo + 256 + tid,  ((const ull*)sAi)[tid + 256]);
        ast(Eo + 512 + tid,  ((const ull*)sCi)[tid]);
        ast(Eo + 768 + tid,  ((const ull*)sCi)[tid + 256]);
        ast(Eo + 1024 + tid, ((const ull*)sJi)[tid]);
        ast(Eo + 1280 + tid, ((const ull*)sJi)[tid + 256]);
        setf(&wr[(l + 1) * 64 + t]);
      }
    }
  }

  // ====== Phase 2: LOCAL kmat (r21 text; G/Fu aliased into sScr) ======
  float (*sG)[NA]  = (float(*)[NA])sScr;
  float (*sFu)[NA] = (float(*)[NA])(sScr + NS * NA);
  auto kmat = [&](int tau, bool hasP, float (*Pm)[NS], float (*Kd)[NS], bool wM) {
    const int ui = tid / 12, uk = tid - 12 * ui;
    float4 cr0 = make_float4(0,0,0,0), cr1 = make_float4(0,0,0,0);
    float4 cr2 = make_float4(0,0,0,0), cr3 = make_float4(0,0,0,0);
    if (tid < 48) {
      const float* Ct = C + (size_t)tau * NA * NA;
      cr0 = *(const float4*)&Ct[(NS + 4 * ui + 0) * NA + 4 * uk];
      cr1 = *(const float4*)&Ct[(NS + 4 * ui + 1) * NA + 4 * uk];
      cr2 = *(const float4*)&Ct[(NS + 4 * ui + 2) * NA + 4 * uk];
      cr3 = *(const float4*)&Ct[(NS + 4 * ui + 3) * NA + 4 * uk];
    }
    if (hasP) {
      if (tid < 96) {
        const int gi = tid / 12, gk = tid - 12 * gi;
        float4 acc[4] = {make_float4(0,0,0,0), make_float4(0,0,0,0),
                         make_float4(0,0,0,0), make_float4(0,0,0,0)};
        tile_outer<NS>(&Pm[0][4 * gi], NS, &sAB[0][4 * gk], NA, acc);
        #pragma unroll
        for (int r = 0; r < 4; ++r) *(float4*)&sG[4 * gi + r][4 * gk] = acc[r];
      }
    } else {
      for (int e = tid; e < NS * NA; e += NTH) sG[e / NA][e % NA] = 0.f;
    }
    __syncthreads();
    if (tid < 48) {
      float4 acc[4] = {cr0, cr1, cr2, cr3};
      tile_outer<NS>(&sAB[0][NS + 4 * ui], NA, &sG[0][4 * uk], NA, acc);
      #pragma unroll
      for (int r = 0; r < 4; ++r) *(float4*)&sFu[4 * ui + r][4 * uk] = acc[r];
    }
    __syncthreads();
    if (wid == 0) {                 // GJ16
      const int col = (lane < 16) ? (NS + lane) : (lane - 16);
      float f[NI];
      #pragma unroll
      for (int i = 0; i < NI; ++i) f[i] = sFu[i][col];
      #pragma unroll
      for (int k = 0; k < NI; ++k) {
        float mi[NI];
        #pragma unroll
        for (int i = 0; i < NI; ++i) mi[i] = rdlane(f[i], k);
        const float inv = 1.0f / mi[k];
        f[k] *= inv;
        #pragma unroll
        for (int i = 0; i < NI; ++i) if (i != k) f[i] -= mi[i] * f[k];
      }
      if (lane >= 16 && lane < 48) {
        const int b = lane - 16;
        #pragma unroll
        for (int i = 0; i < NI; ++i) Kd[i][b] = f[i];
      }
    }
    __syncthreads();
    if (wM && tid < 64) {           // M = A - B·K -> Mall[tau]
      const int ma = tid >> 3, mb = tid & 7;
      float4 a0 = *(const float4*)&sAB[4 * ma + 0][4 * mb];
      float4 a1 = *(const float4*)&sAB[4 * ma + 1][4 * mb];
      float4 a2 = *(const float4*)&sAB[4 * ma + 2][4 * mb];
      float4 a3 = *(const float4*)&sAB[4 * ma + 3][4 * mb];
      #pragma unroll
      for (int q = 0; q < 4; ++q) {
        const float4 vf0 = *(const float4*)&sAB[4 * ma + 0][NS + 4 * q];
        const float4 vf1 = *(const float4*)&sAB[4 * ma + 1][NS + 4 * q];
        const float4 vf2 = *(const float4*)&sAB[4 * ma + 2][NS + 4 * q];
        const float4 vf3 = *(const float4*)&sAB[4 * ma + 3][NS + 4 * q];
        #pragma unroll
        for (int d = 0; d < 4; ++d) {
          const float4 vkk = *(const float4*)&Kd[4 * q + d][4 * mb];
          const float s0 = (d == 0) ? vf0.x : (d == 1) ? vf0.y : (d == 2) ? vf0.z : vf0.w;
          const float s1 = (d == 0) ? vf1.x : (d == 1) ? vf1.y : (d == 2) ? vf1.z : vf1.w;
          const float s2 = (d == 0) ? vf2.x : (d == 1) ? vf2.y : (d == 2) ? vf2.z : vf2.w;
          const float s3 = (d == 0) ? vf3.x : (d == 1) ? vf3.y : (d == 2) ? vf3.z : vf3.w;
          fms4(a0, s0, vkk); fms4(a1, s1, vkk); fms4(a2, s2, vkk); fms4(a3, s3, vkk);
        }
      }
      ull* Mt = (ull*)(Mall + (size_t)tau * NS * NS);
      ast4(Mt + (4 * ma + 0) * 16 + 2 * mb, a0);
      ast4(Mt + (4 * ma + 1) * 16 + 2 * mb, a1);
      ast4(Mt + (4 * ma + 2) * 16 + 2 * mb, a2);
      ast4(Mt + (4 * ma + 3) * 16 + 2 * mb, a3);
    }
    __syncthreads();
  };

  if (t >= 1) kmat(t - 1, true, sJi, sK, true);
  if (t == TT - 1) kmat(TT - 1, false, nullptr, sK2, false);  // K_63 (P_64=0)
  setf(&mf[t]);

  // ========== Phase 3: per-block LOCAL rollout (x up to own t) =============
  {
    if (tid >= 1 && tid <= t) {       // need only mf[1..t]
      while (fld(&mf[tid]) == 0) __builtin_amdgcn_s_sleep(1);
    }
    __syncthreads();
    if (wid == 0) {
      const int i = lane;
      if (i < NS) {
        const ull* Mg = (const ull*)Mall;
        float4 mA[8], mB[8];
        float x = x0[i];
        if (t == 1) sXt1[i] = x;
        if (t >= 1) {
          #pragma unroll
          for (int q = 0; q < 8; ++q) mA[q] = ald4(Mg + 0 * 512 + i * 16 + 2 * q);
        }
        if (t >= 2) {
          #pragma unroll
          for (int q = 0; q < 8; ++q) mB[q] = ald4(Mg + 1 * 512 + i * 16 + 2 * q);
        }
        for (int s = 0; s < t; s += 2) {
          x = step_dot(mA, x);
          if (s + 1 == t - 1) sXt1[i] = x;
          if (s + 2 < t) {
            #pragma unroll
            for (int q = 0; q < 8; ++q)
              mA[q] = ald4(Mg + (s + 2) * 512 + i * 16 + 2 * q);
          }
          if (s + 1 < t) {
            x = step_dot(mB, x);
            if (s + 2 == t - 1) sXt1[i] = x;
            if (s + 3 < t) {
              #pragma unroll
              for (int q = 0; q < 8; ++q)
                mB[q] = ald4(Mg + (s + 3) * 512 + i * 16 + 2 * q);
            }
          }
        }
        sXt0[i] = x;
        out[t * NA + i] = x;
      }
    }
    __syncthreads();
  }

  // ========== Phase 4: u_{t-1} (local K), mu_t (local J) ==================
  {
    if (t >= 1 && tid < NI) {         // u_{t-1} = -K_{t-1} x_{t-1}
      const float4* Kr = (const float4*)&sK[tid][0];
      const float4* xr = (const float4*)sXt1;
      float acc = 0.f;
      #pragma unroll
      for (int q = 0; q < 8; ++q) acc += dot4(Kr[q], xr[q]);
      out[(t - 1) * NA + NS + tid] = -acc;
    } else if (tid >= NI && tid < NI + NS) {  // mu_t = +/- P_t x_t
      const int i = tid - NI;
      const float4* Pr = (const float4*)&sJi[i][0];
      const float4* xr = (const float4*)sXt0;
      float acc = 0.f;
      #pragma unroll
      for (int q = 0; q < 8; ++q) acc += dot4(Pr[q], xr[q]);
      out[NA * TT + t * NS + i] = (t == 0) ? -acc : acc;
    } else if (t == TT - 1 && tid >= 192 && tid < 192 + NI) {  // u_63
      const int i = tid - 192;
      const float4* Kr = (const float4*)&sK2[i][0];
      const float4* xr = (const float4*)sXt0;
      float acc = 0.f;
      #pragma unroll
      for (int q = 0; q < 8; ++q) acc += dot4(Kr[q], xr[q]);
      out[(TT - 1) * NA + NS + i] = -acc;
    }
  }
}

} // namespace

extern "C" void kernel_launch(void* const* d_in, const int* in_sizes, int n_in,
                              void* d_out, int out_size, void* d_ws, size_t ws_size,
                              hipStream_t stream) {
  const float* A  = (const float*)d_in[0];
  const float* Bm = (const float*)d_in[1];
  const float* C  = (const float*)d_in[2];
  // d_in[3] is T (==64, compile-time constant here)
  const float* x0 = (const float*)d_in[4];
  float* out = (float*)d_out;

  float* Sb0 = (float*)d_ws;                           // 64*3072 floats
  float* Sb1 = Sb0 + (size_t)TT * 3072;                // 64*3072
  float* Mall = Sb1 + (size_t)TT * 3072;               // 64*1024
  unsigned* flg = (unsigned*)(Mall + (size_t)TT * NS * NS); // wr 448|rd 384|mf 64

  hipMemsetAsync(flg, 0, 4096, stream);
  hipLaunchKernelGGL(lqr_all, dim3(NBLK), dim3(NTH), 0, stream,
                     A, Bm, C, x0, out, Sb0, Sb1, Mall, flg);
}

// Round 23
// 122.713 us; speedup vs baseline: 1.0385x; 1.0385x over previous
//
#include <hip/hip_runtime.h>

// LQR KKT via temporally-parallel Riccati scan — fused persistent kernel.
// Round-23 = r21 (best: 126.5us) with EXACT DIVIDES -> v_rcp_f32 in every
// Gauss-Jordan pivot chain (combine GJ32, init GJ16, kmat GJ16). The divide
// sits on the 32-deep serial pivot chain of each combine; rcpf removes the
// div_scale/div_fmas latency (~0.5-1us/combine x 6 levels + init + kmat).
// rcpf proven safe: r9/r17 kmat used it with absmax 4.0; threshold 39.5.
// Everything else byte-identical to r21.
// Dims: n_state=32, n_input=16, n_all=48, T=64. Anchor: r21 126.5.

namespace {

constexpr int NS  = 32;
constexpr int NI  = 16;
constexpr int NA  = 48;
constexpr int TT  = 64;
constexpr int NTH = 256;
constexpr int NBLK = 64;

using ull = unsigned long long;

__device__ __forceinline__ void fma4(float4& a, float s, const float4& b) {
  a.x += s * b.x; a.y += s * b.y; a.z += s * b.z; a.w += s * b.w;
}
__device__ __forceinline__ void fms4(float4& a, float s, const float4& b) {
  a.x -= s * b.x; a.y -= s * b.y; a.z -= s * b.z; a.w -= s * b.w;
}
__device__ __forceinline__ float dot4(const float4& a, const float4& b) {
  return a.x * b.x + a.y * b.y + a.z * b.z + a.w * b.w;
}
__device__ __forceinline__ float rdlane(float v, int l) {
  return __int_as_float(__builtin_amdgcn_readlane(__float_as_int(v), l));
}

// agent-scope relaxed atomic movement (r13..r21-proven primitive)
__device__ __forceinline__ ull ald(const ull* p) {
  return __hip_atomic_load(p, __ATOMIC_RELAXED, __HIP_MEMORY_SCOPE_AGENT);
}
__device__ __forceinline__ void ast(ull* p, ull v) {
  __hip_atomic_store(p, v, __ATOMIC_RELAXED, __HIP_MEMORY_SCOPE_AGENT);
}
__device__ __forceinline__ ull pack2(float x, float y) {
  return (ull)__float_as_uint(x) | ((ull)__float_as_uint(y) << 32);
}
__device__ __forceinline__ float2 unpack2(ull v) {
  return make_float2(__uint_as_float((unsigned)v),
                     __uint_as_float((unsigned)(v >> 32)));
}
__device__ __forceinline__ float4 ald4(const ull* p) {
  ull lo = ald(p), hi = ald(p + 1);
  float2 a = unpack2(lo), b = unpack2(hi);
  return make_float4(a.x, a.y, b.x, b.y);
}
__device__ __forceinline__ void ast4(ull* p, const float4& v) {
  ast(p, pack2(v.x, v.y)); ast(p + 1, pack2(v.z, v.w));
}

// ---- point-to-point flags ----
__device__ __forceinline__ unsigned fld(const unsigned* f) {
  return __hip_atomic_load(f, __ATOMIC_RELAXED, __HIP_MEMORY_SCOPE_AGENT);
}
__device__ __forceinline__ void fst(unsigned* f) {
  __hip_atomic_store(f, 1u, __ATOMIC_RELAXED, __HIP_MEMORY_SCOPE_AGENT);
}
__device__ __forceinline__ void waitf(const unsigned* f) {
  if (threadIdx.x == 0)
    while (fld(f) == 0) __builtin_amdgcn_s_sleep(1);
  __syncthreads();
}
__device__ __forceinline__ void setf(unsigned* f) {
  asm volatile("s_waitcnt vmcnt(0)" ::: "memory");
  __syncthreads();
  if (threadIdx.x == 0) fst(f);
}

template<int K>
__device__ __forceinline__ void tile_outer(const float* Acol0, int lda,
                                           const float* Bcol0, int ldb,
                                           float4 acc[4]) {
  #pragma unroll
  for (int m = 0; m < K; ++m) {
    const float4 va = *(const float4*)(Acol0 + m * lda);
    const float4 vb = *(const float4*)(Bcol0 + m * ldb);
    fma4(acc[0], va.x, vb); fma4(acc[1], va.y, vb);
    fma4(acc[2], va.z, vb); fma4(acc[3], va.w, vb);
  }
}

template<int KQ>
__device__ __forceinline__ void tile_dot(const float* Arow0, int lda,
                                         const float* Brow0, int ldb,
                                         float acc[4][4]) {
  #pragma unroll
  for (int q = 0; q < KQ; ++q) {
    float4 va[4], vb[4];
    #pragma unroll
    for (int r = 0; r < 4; ++r) va[r] = *(const float4*)(Arow0 + r * lda + 4 * q);
    #pragma unroll
    for (int c = 0; c < 4; ++c) vb[c] = *(const float4*)(Brow0 + c * ldb + 4 * q);
    #pragma unroll
    for (int r = 0; r < 4; ++r)
      #pragma unroll
      for (int c = 0; c < 4; ++c) acc[r][c] += dot4(va[r], vb[c]);
  }
}

__device__ __forceinline__ float step_dot(const float4 m[8], float x) {
  float a0 = 0.f, a1 = 0.f, a2 = 0.f, a3 = 0.f;
  #pragma unroll
  for (int q = 0; q < 8; ++q) {
    a0 += rdlane(x, 4 * q + 0) * m[q].x;
    a1 += rdlane(x, 4 * q + 1) * m[q].y;
    a2 += rdlane(x, 4 * q + 2) * m[q].z;
    a3 += rdlane(x, 4 * q + 3) * m[q].w;
  }
  return (a0 + a1) + (a2 + a3);
}

// #binary levels element rm participates in (its final version index)
__device__ __forceinline__ int nlev(int rm) {
  return (rm == TT - 1) ? 0 : (32 - __clz(TT - 1 - rm));
}

__global__ __launch_bounds__(NTH, 1) void lqr_all(
    const float* __restrict__ A, const float* __restrict__ Bm,
    const float* __restrict__ C, const float* __restrict__ x0,
    float* __restrict__ out,
    float* __restrict__ Sb0, float* __restrict__ Sb1,
    float* __restrict__ Mall, unsigned* __restrict__ flg) {
  __shared__ float sC [NA][NA];
  __shared__ float sAB[NS][NA];
  __shared__ float sRiST[NS][NI];   // S R^{-1}
  __shared__ float sBRi [NS][NI];   // B R^{-1}
  __shared__ float sAi[NS][NS], sCi[NS][NS], sJi[NS][NS];   // own element
  __shared__ float sAj[NS][NS], sCj[NS][NS], sJj[NS][NS];
  __shared__ float sAjT[NS][36];    // padded: transpose write 32-way -> 4-way
  __shared__ float sV[NS][NS], sU[NS][NS];
  __shared__ float sY1[NS][NS], sY2[NS][NS], sW[NS][NS];
  __shared__ float sX[NS][NS], sZm[NS][NS];
  __shared__ float sG[NS][NA], sFu[NI][NA], sK[NI][NS], sK2[NI][NS];
  __shared__ float sXt0[NS], sXt1[NS];

  // XCD-locality swizzle (r19-proven)
  const int t = ((blockIdx.x & 7) << 3) | (blockIdx.x >> 3);
  const int tid = threadIdx.x, lane = tid & 63, wid = tid >> 6;
  unsigned* wr = flg;              // 7*64
  unsigned* rd = flg + 448;        // 6*64
  unsigned* mf = flg + 832;        // 64

  // ================= Phase 0: element init (r21 text; rcpf pivots) ========
  {
    const float* Ct = C + (size_t)t * NA * NA;
    for (int e = tid; e < NA * NA; e += NTH) sC[e / NA][e % NA] = Ct[e];
    for (int e = tid; e < NS * NA; e += NTH) {
      int i = e / NA, j = e % NA;
      sAB[i][j] = (j < NS) ? A[i * NS + j] : Bm[i * NI + (j - NS)];
    }
    __syncthreads();
    // wave0: GJ16 [R|S^T] -> R^-1 S^T (stored as S R^-1); wave1: [R|B^T]
    if (wid < 2 && lane < 48) {
      const int c = lane;
      float f[NI];
      if (c < NI) {
        #pragma unroll
        for (int i = 0; i < NI; ++i) f[i] = sC[NS + i][NS + c];
      } else {
        const int a = c - NI;
        if (wid == 0) {
          #pragma unroll
          for (int i = 0; i < NI; ++i) f[i] = sC[a][NS + i];
        } else {
          #pragma unroll
          for (int i = 0; i < NI; ++i) f[i] = sAB[a][NS + i];
        }
      }
      #pragma unroll
      for (int k = 0; k < NI; ++k) {
        float mi[NI];
        #pragma unroll
        for (int i = 0; i < NI; ++i) mi[i] = rdlane(f[i], k);
        const float inv = __builtin_amdgcn_rcpf(mi[k]);
        f[k] *= inv;
        #pragma unroll
        for (int i = 0; i < NI; ++i) if (i != k) f[i] -= mi[i] * f[k];
      }
      if (c >= NI) {
        const int a = c - NI;
        float* D = (wid == 0) ? &sRiST[a][0] : &sBRi[a][0];
        #pragma unroll
        for (int i = 0; i < NI; ++i) D[i] = f[i];
      }
    }
    __syncthreads();
    ull* outA = (ull*)(Sb0 + (size_t)t * 3072);
    ull* outC = outA + 512;
    ull* outJ = outA + 1024;
    if (tid < 64) {                   // J_e = Q - (S R^-1) S^T
      const int a = tid >> 3, b = tid & 7;
      float acc[4][4];
      #pragma unroll
      for (int r = 0; r < 4; ++r)
        #pragma unroll
        for (int c = 0; c < 4; ++c) acc[r][c] = 0.f;
      tile_dot<4>(&sRiST[4 * a][0], NI, &sC[4 * b][NS], NA, acc);
      #pragma unroll
      for (int r = 0; r < 4; ++r) {
        const float4 q4 = *(const float4*)&sC[4 * a + r][4 * b];
        const float4 v = make_float4(q4.x - acc[r][0], q4.y - acc[r][1],
                                     q4.z - acc[r][2], q4.w - acc[r][3]);
        *(float4*)&sJi[4 * a + r][4 * b] = v;
        ast4(outJ + ((4 * a + r) * NS + 4 * b) / 2, v);
      }
    } else if (tid < 128) {           // A_e = A - (B R^-1) S^T
      const int q = tid - 64, a = q >> 3, b = q & 7;
      float acc[4][4];
      #pragma unroll
      for (int r = 0; r < 4; ++r)
        #pragma unroll
        for (int c = 0; c < 4; ++c) acc[r][c] = 0.f;
      tile_dot<4>(&sBRi[4 * a][0], NI, &sC[4 * b][NS], NA, acc);
      #pragma unroll
      for (int r = 0; r < 4; ++r) {
        const float4 a4 = *(const float4*)&sAB[4 * a + r][4 * b];
        const float4 v = make_float4(a4.x - acc[r][0], a4.y - acc[r][1],
                                     a4.z - acc[r][2], a4.w - acc[r][3]);
        *(float4*)&sAi[4 * a + r][4 * b] = v;
        ast4(outA + ((4 * a + r) * NS + 4 * b) / 2, v);
      }
    } else if (tid < 192) {           // C_e = (B R^-1) B^T
      const int q = tid - 128, a = q >> 3, b = q & 7;
      float acc[4][4];
      #pragma unroll
      for (int r = 0; r < 4; ++r)
        #pragma unroll
        for (int c = 0; c < 4; ++c) acc[r][c] = 0.f;
      tile_dot<4>(&sBRi[4 * a][0], NI, &sAB[4 * b][NS], NA, acc);
      #pragma unroll
      for (int r = 0; r < 4; ++r) {
        const float4 v = make_float4(acc[r][0], acc[r][1], acc[r][2], acc[r][3]);
        *(float4*)&sCi[4 * a + r][4 * b] = v;
        ast4(outC + ((4 * a + r) * NS + 4 * b) / 2, v);
      }
    }
  }
  setf(&wr[0 * 64 + t]);

  // fast combine (r18/r19; rcpf pivots): own ⊗ remote via dual-RHS GJ32
  auto combine = [&]() {
    #pragma unroll
    for (int r = 0; r < 4; ++r) {
      const int e = tid + 256 * r, i = e >> 5, j = e & 31;
      sAjT[j][i] = sAj[i][j];
    }
    if (tid < 64) {                 // Ph1: X = I + Ci·Jj
      const int a = tid >> 3, b = tid & 7;
      float4 acc[4] = {make_float4(0,0,0,0), make_float4(0,0,0,0),
                       make_float4(0,0,0,0), make_float4(0,0,0,0)};
      tile_outer<NS>(&sCi[0][4 * a], NS, &sJj[0][4 * b], NS, acc);
      if (a == b) { acc[0].x += 1.f; acc[1].y += 1.f; acc[2].z += 1.f; acc[3].w += 1.f; }
      #pragma unroll
      for (int r = 0; r < 4; ++r) *(float4*)&sX[4 * a + r][4 * b] = acc[r];
    }
    __syncthreads();
    // Ph2: dual GJ32 — wave0 [X|Ai]->V, wave1 [X|Ci]->U
    if (wid < 2) {
      const int c = lane;
      float f[NS];
      if (c < NS) {
        #pragma unroll
        for (int i = 0; i < NS; ++i) f[i] = sX[i][c];
      } else if (wid == 0) {
        #pragma unroll
        for (int i = 0; i < NS; ++i) f[i] = sAi[i][c - NS];
      } else {
        #pragma unroll
        for (int i = 0; i < NS; ++i) f[i] = sCi[i][c - NS];
      }
      #pragma unroll
      for (int k = 0; k < NS; ++k) {
        float mi[NS];
        #pragma unroll
        for (int i = 0; i < NS; ++i) mi[i] = rdlane(f[i], k);
        const float inv = __builtin_amdgcn_rcpf(mi[k]);
        f[k] *= inv;
        #pragma unroll
        for (int i = 0; i < NS; ++i) if (i != k) f[i] -= mi[i] * f[k];
      }
      if (c >= NS) {
        const int col = c - NS;
        if (wid == 0) {
          #pragma unroll
          for (int i = 0; i < NS; ++i) sV[i][col] = f[i];
        } else {
          #pragma unroll
          for (int i = 0; i < NS; ++i) sU[i][col] = f[i];
        }
      }
    }
    __syncthreads();
    // Ph3: P1 = Jj·V -> sW | A' = Aj·V -> sX | W2 = Aj·U -> sZm
    if (tid < 192) {
      const int grp = tid >> 6, q = tid & 63, a = q >> 3, b = q & 7;
      float4 acc[4] = {make_float4(0,0,0,0), make_float4(0,0,0,0),
                       make_float4(0,0,0,0), make_float4(0,0,0,0)};
      if (grp == 0) {
        tile_outer<NS>(&sJj[0][4 * a], NS, &sV[0][4 * b], NS, acc);
        #pragma unroll
        for (int r = 0; r < 4; ++r) *(float4*)&sW[4 * a + r][4 * b] = acc[r];
      } else if (grp == 1) {
        tile_outer<NS>(&sAjT[0][4 * a], 36, &sV[0][4 * b], NS, acc);
        #pragma unroll
        for (int r = 0; r < 4; ++r) *(float4*)&sX[4 * a + r][4 * b] = acc[r];
      } else {
        tile_outer<NS>(&sAjT[0][4 * a], 36, &sU[0][4 * b], NS, acc);
        #pragma unroll
        for (int r = 0; r < 4; ++r) *(float4*)&sZm[4 * a + r][4 * b] = acc[r];
      }
    }
    __syncthreads();
    // Ph4: J' = Ai^T·P1 + Ji -> sY1 | C' = W2·Aj^T + Cj -> sY2
    if (tid < 64) {
      const int a = tid >> 3, b = tid & 7;
      float4 acc[4] = {make_float4(0,0,0,0), make_float4(0,0,0,0),
                       make_float4(0,0,0,0), make_float4(0,0,0,0)};
      tile_outer<NS>(&sAi[0][4 * a], NS, &sW[0][4 * b], NS, acc);
      #pragma unroll
      for (int r = 0; r < 4; ++r) {
        const float4 j4 = *(const float4*)&sJi[4 * a + r][4 * b];
        acc[r].x += j4.x; acc[r].y += j4.y; acc[r].z += j4.z; acc[r].w += j4.w;
        *(float4*)&sY1[4 * a + r][4 * b] = acc[r];
      }
    } else if (tid < 128) {
      const int q = tid - 64, a = q >> 3, b = q & 7;
      float acc[4][4];
      #pragma unroll
      for (int r = 0; r < 4; ++r)
        #pragma unroll
        for (int c = 0; c < 4; ++c) acc[r][c] = 0.f;
      tile_dot<8>(&sZm[4 * a][0], NS, &sAj[4 * b][0], NS, acc);
      #pragma unroll
      for (int r = 0; r < 4; ++r) {
        const float4 c4 = *(const float4*)&sCj[4 * a + r][4 * b];
        *(float4*)&sY2[4 * a + r][4 * b] =
            make_float4(acc[r][0] + c4.x, acc[r][1] + c4.y,
                        acc[r][2] + c4.z, acc[r][3] + c4.w);
      }
    }
    __syncthreads();
    ((ull*)sAi)[tid] = ((const ull*)sX)[tid];
    ((ull*)sAi)[tid + 256] = ((const ull*)sX)[tid + 256];
    ((ull*)sCi)[tid] = ((const ull*)sY2)[tid];
    ((ull*)sCi)[tid + 256] = ((const ull*)sY2)[tid + 256];
    ((ull*)sJi)[tid] = ((const ull*)sY1)[tid];
    ((ull*)sJi)[tid + 256] = ((const ull*)sY1)[tid + 256];
    __syncthreads();
  };

  // ============ Phase 1: radix-2 scan, dataflow-synced ============
  for (int l = 0; l < 6; ++l) {
    const int off = 1 << l;
    const int rm = t + off;
    if (rm < TT) {
      const int nlv = nlev(rm);
      const int v = (l < nlv) ? l : nlv;      // frozen-final fallback
      const float* Sin = (v & 1) ? Sb1 : Sb0;
      float* Sout = ((l + 1) & 1) ? Sb1 : Sb0;
      ull* Eo = (ull*)(Sout + (size_t)t * 3072);
      waitf(&wr[v * 64 + rm]);
      const ull* Ej = (const ull*)(Sin + (size_t)rm * 3072);
      {
        ull r0 = ald(Ej + tid),        r1 = ald(Ej + 256 + tid);
        ull r2 = ald(Ej + 512 + tid),  r3 = ald(Ej + 768 + tid);
        ull r4 = ald(Ej + 1024 + tid), r5 = ald(Ej + 1280 + tid);
        ((ull*)sAj)[tid] = r0; ((ull*)sAj)[tid + 256] = r1;
        ((ull*)sCj)[tid] = r2; ((ull*)sCj)[tid + 256] = r3;
        ((ull*)sJj)[tid] = r4; ((ull*)sJj)[tid + 256] = r5;
      }
      __syncthreads();
      if (v == l && tid == 0) fst(&rd[l * 64 + rm]);
      combine();
      // Level-5 publish is DEAD (max version any reader uses is 5); skip.
      if (l < 5) {
        if (l >= 1 && t >= (off >> 1)) waitf(&rd[(l - 1) * 64 + t]);  // WAR
        ast(Eo + tid,        ((const ull*)sAi)[tid]);
        ast(Eo + 256 + tid,  ((const ull*)sAi)[tid + 256]);
        ast(Eo + 512 + tid,  ((const ull*)sCi)[tid]);
        ast(Eo + 768 + tid,  ((const ull*)sCi)[tid + 256]);
        ast(Eo + 1024 + tid, ((const ull*)sJi)[tid]);
        ast(Eo + 1280 + tid, ((const ull*)sJi)[tid + 256]);
        setf(&wr[(l + 1) * 64 + t]);
      }
    }
  }

  // ====== Phase 2: LOCAL kmat (r21 text; rcpf pivots) ======
  auto kmat = [&](int tau, bool hasP, float (*Pm)[NS], float (*Kd)[NS], bool wM) {
    const int ui = tid / 12, uk = tid - 12 * ui;
    float4 cr0 = make_float4(0,0,0,0), cr1 = make_float4(0,0,0,0);
    float4 cr2 = make_float4(0,0,0,0), cr3 = make_float4(0,0,0,0);
    if (tid < 48) {
      const float* Ct = C + (size_t)tau * NA * NA;
      cr0 = *(const float4*)&Ct[(NS + 4 * ui + 0) * NA + 4 * uk];
      cr1 = *(const float4*)&Ct[(NS + 4 * ui + 1) * NA + 4 * uk];
      cr2 = *(const float4*)&Ct[(NS + 4 * ui + 2) * NA + 4 * uk];
      cr3 = *(const float4*)&Ct[(NS + 4 * ui + 3) * NA + 4 * uk];
    }
    if (hasP) {
      if (tid < 96) {
        const int gi = tid / 12, gk = tid - 12 * gi;
        float4 acc[4] = {make_float4(0,0,0,0), make_float4(0,0,0,0),
                         make_float4(0,0,0,0), make_float4(0,0,0,0)};
        tile_outer<NS>(&Pm[0][4 * gi], NS, &sAB[0][4 * gk], NA, acc);
        #pragma unroll
        for (int r = 0; r < 4; ++r) *(float4*)&sG[4 * gi + r][4 * gk] = acc[r];
      }
    } else {
      for (int e = tid; e < NS * NA; e += NTH) sG[e / NA][e % NA] = 0.f;
    }
    __syncthreads();
    if (tid < 48) {
      float4 acc[4] = {cr0, cr1, cr2, cr3};
      tile_outer<NS>(&sAB[0][NS + 4 * ui], NA, &sG[0][4 * uk], NA, acc);
      #pragma unroll
      for (int r = 0; r < 4; ++r) *(float4*)&sFu[4 * ui + r][4 * uk] = acc[r];
    }
    __syncthreads();
    if (wid == 0) {                 // GJ16
      const int col = (lane < 16) ? (NS + lane) : (lane - 16);
      float f[NI];
      #pragma unroll
      for (int i = 0; i < NI; ++i) f[i] = sFu[i][col];
      #pragma unroll
      for (int k = 0; k < NI; ++k) {
        float mi[NI];
        #pragma unroll
        for (int i = 0; i < NI; ++i) mi[i] = rdlane(f[i], k);
        const float inv = __builtin_amdgcn_rcpf(mi[k]);
        f[k] *= inv;
        #pragma unroll
        for (int i = 0; i < NI; ++i) if (i != k) f[i] -= mi[i] * f[k];
      }
      if (lane >= 16 && lane < 48) {
        const int b = lane - 16;
        #pragma unroll
        for (int i = 0; i < NI; ++i) Kd[i][b] = f[i];
      }
    }
    __syncthreads();
    if (wM && tid < 64) {           // M = A - B·K -> Mall[tau]
      const int ma = tid >> 3, mb = tid & 7;
      float4 a0 = *(const float4*)&sAB[4 * ma + 0][4 * mb];
      float4 a1 = *(const float4*)&sAB[4 * ma + 1][4 * mb];
      float4 a2 = *(const float4*)&sAB[4 * ma + 2][4 * mb];
      float4 a3 = *(const float4*)&sAB[4 * ma + 3][4 * mb];
      #pragma unroll
      for (int q = 0; q < 4; ++q) {
        const float4 vf0 = *(const float4*)&sAB[4 * ma + 0][NS + 4 * q];
        const float4 vf1 = *(const float4*)&sAB[4 * ma + 1][NS + 4 * q];
        const float4 vf2 = *(const float4*)&sAB[4 * ma + 2][NS + 4 * q];
        const float4 vf3 = *(const float4*)&sAB[4 * ma + 3][NS + 4 * q];
        #pragma unroll
        for (int d = 0; d < 4; ++d) {
          const float4 vkk = *(const float4*)&Kd[4 * q + d][4 * mb];
          const float s0 = (d == 0) ? vf0.x : (d == 1) ? vf0.y : (d == 2) ? vf0.z : vf0.w;
          const float s1 = (d == 0) ? vf1.x : (d == 1) ? vf1.y : (d == 2) ? vf1.z : vf1.w;
          const float s2 = (d == 0) ? vf2.x : (d == 1) ? vf2.y : (d == 2) ? vf2.z : vf2.w;
          const float s3 = (d == 0) ? vf3.x : (d == 1) ? vf3.y : (d == 2) ? vf3.z : vf3.w;
          fms4(a0, s0, vkk); fms4(a1, s1, vkk); fms4(a2, s2, vkk); fms4(a3, s3, vkk);
        }
      }
      ull* Mt = (ull*)(Mall + (size_t)tau * NS * NS);
      ast4(Mt + (4 * ma + 0) * 16 + 2 * mb, a0);
      ast4(Mt + (4 * ma + 1) * 16 + 2 * mb, a1);
      ast4(Mt + (4 * ma + 2) * 16 + 2 * mb, a2);
      ast4(Mt + (4 * ma + 3) * 16 + 2 * mb, a3);
    }
    __syncthreads();
  };

  if (t >= 1) kmat(t - 1, true, sJi, sK, true);
  if (t == TT - 1) kmat(TT - 1, false, nullptr, sK2, false);  // K_63 (P_64=0)
  setf(&mf[t]);

  // ========== Phase 3: per-block LOCAL rollout (x up to own t) =============
  {
    // need only M_0..M_{t-1} = mf[1..t] (producer of M_{s-1} is block s)
    if (tid >= 1 && tid <= t) {
      while (fld(&mf[tid]) == 0) __builtin_amdgcn_s_sleep(1);
    }
    __syncthreads();
    if (wid == 0) {
      const int i = lane;
      if (i < NS) {
        const ull* Mg = (const ull*)Mall;
        float4 mA[8], mB[8];
        float x = x0[i];
        if (t == 1) sXt1[i] = x;    // x_0 is x_{t-1} when t==1
        if (t >= 1) {
          #pragma unroll
          for (int q = 0; q < 8; ++q) mA[q] = ald4(Mg + 0 * 512 + i * 16 + 2 * q);
        }
        if (t >= 2) {
          #pragma unroll
          for (int q = 0; q < 8; ++q) mB[q] = ald4(Mg + 1 * 512 + i * 16 + 2 * q);
        }
        for (int s = 0; s < t; s += 2) {
          x = step_dot(mA, x);                    // x_{s+1}
          if (s + 1 == t - 1) sXt1[i] = x;
          if (s + 2 < t) {
            #pragma unroll
            for (int q = 0; q < 8; ++q)
              mA[q] = ald4(Mg + (s + 2) * 512 + i * 16 + 2 * q);
          }
          if (s + 1 < t) {
            x = step_dot(mB, x);                  // x_{s+2}
            if (s + 2 == t - 1) sXt1[i] = x;
            if (s + 3 < t) {
              #pragma unroll
              for (int q = 0; q < 8; ++q)
                mB[q] = ald4(Mg + (s + 3) * 512 + i * 16 + 2 * q);
            }
          }
        }
        sXt0[i] = x;                // x_t
        out[t * NA + i] = x;        // own tau x-slice
      }
    }
    __syncthreads();
  }

  // ========== Phase 4: u_{t-1} (local K), mu_t (local J) ==================
  {
    if (t >= 1 && tid < NI) {       // u_{t-1} = -K_{t-1} x_{t-1}
      const float4* Kr = (const float4*)&sK[tid][0];
      const float4* xr = (const float4*)sXt1;
      float acc = 0.f;
      #pragma unroll
      for (int q = 0; q < 8; ++q) acc += dot4(Kr[q], xr[q]);
      out[(t - 1) * NA + NS + tid] = -acc;
    } else if (tid >= NI && tid < NI + NS) {  // mu_t = +/- P_t x_t
      const int i = tid - NI;
      const float4* Pr = (const float4*)&sJi[i][0];
      const float4* xr = (const float4*)sXt0;
      float acc = 0.f;
      #pragma unroll
      for (int q = 0; q < 8; ++q) acc += dot4(Pr[q], xr[q]);
      out[NA * TT + t * NS + i] = (t == 0) ? -acc : acc;
    } else if (t == TT - 1 && tid >= 192 && tid < 192 + NI) {  // u_63
      const int i = tid - 192;
      const float4* Kr = (const float4*)&sK2[i][0];
      const float4* xr = (const float4*)sXt0;
      float acc = 0.f;
      #pragma unroll
      for (int q = 0; q < 8; ++q) acc += dot4(Kr[q], xr[q]);
      out[(TT - 1) * NA + NS + i] = -acc;
    }
  }
}

} // namespace

extern "C" void kernel_launch(void* const* d_in, const int* in_sizes, int n_in,
                              void* d_out, int out_size, void* d_ws, size_t ws_size,
                              hipStream_t stream) {
  const float* A  = (const float*)d_in[0];
  const float* Bm = (const float*)d_in[1];
  const float* C  = (const float*)d_in[2];
  // d_in[3] is T (==64, compile-time constant here)
  const float* x0 = (const float*)d_in[4];
  float* out = (float*)d_out;

  float* Sb0 = (float*)d_ws;                           // 64*3072 floats
  float* Sb1 = Sb0 + (size_t)TT * 3072;                // 64*3072
  float* Mall = Sb1 + (size_t)TT * 3072;               // 64*1024
  unsigned* flg = (unsigned*)(Mall + (size_t)TT * NS * NS); // wr 448|rd 384|mf 64

  hipMemsetAsync(flg, 0, 4096, stream);
  hipLaunchKernelGGL(lqr_all, dim3(NBLK), dim3(NTH), 0, stream,
                     A, Bm, C, x0, out, Sb0, Sb1, Mall, flg);
}